// Round 5
// baseline (483.691 us; speedup 1.0000x reference)
//
#include <hip/hip_runtime.h>
#include <hip/hip_bf16.h>

#define B_ 4096
#define N_ 64
#define D_ 128
#define H_ 2
#define M_ 384
#define DK_ 192
#define NB 4
#define PADROW 392   // bf16 row stride (r3-verified zero-conflict)

// ws float offsets
#define WS_WKEFF 64
#define WS_W1T   1024
#define WS_W2T   66560
#define WS_WVB   82944                      // 147456 ushort = 73728 f32 slots
#define WS_WFCB  156672                     // 147456 ushort
#define WS_CTXB  230400                     // 4096*768 ushort = 1572864 f32 slots
#define WS_OUTVB 1803264                    // 4096*384 ushort = 786432 f32 slots
#define WS_R     2589696                    // 4096*384 f32
#define WS_TOTAL 4162560

typedef __attribute__((ext_vector_type(8))) short bf16x8;
typedef __attribute__((ext_vector_type(4))) float f32x4;

__device__ __forceinline__ unsigned pk2(float a, float b) {
    __hip_bfloat16 x = __float2bfloat16(a), y = __float2bfloat16(b);
    unsigned short ux = __builtin_bit_cast(unsigned short, x);
    unsigned short uy = __builtin_bit_cast(unsigned short, y);
    return (unsigned)ux | ((unsigned)uy << 16);
}
__device__ __forceinline__ float bflo(int v) { return __builtin_bit_cast(float, (unsigned)v << 16); }
__device__ __forceinline__ float bfhi(int v) { return __builtin_bit_cast(float, (unsigned)v & 0xffff0000u); }
__device__ __forceinline__ unsigned short bf1(float a) {
    return __builtin_bit_cast(unsigned short, __float2bfloat16(a));
}

// ---------------------------------------------------------------- prep: mask probe + wk_eff + W1^T/W2^T + bf16 packs
__global__ __launch_bounds__(256) void prep2(
    const float* __restrict__ Wk, const float* __restrict__ wmap,
    const float* __restrict__ W1, const float* __restrict__ W2,
    const float* __restrict__ Wv, const float* __restrict__ Wfc,
    const void* __restrict__ mask, int* __restrict__ flag,
    float* __restrict__ wkeff, float* __restrict__ W1t, float* __restrict__ W2t,
    unsigned short* __restrict__ Wvb, unsigned short* __restrict__ Wfcb) {
    const int tid = threadIdx.x;
    if (blockIdx.x == 0 && tid == 0) {
        const unsigned int* u = (const unsigned int*)mask;
        bool all01 = true, allf = true;
        for (int i = 0; i < 64; ++i) {
            unsigned int v = u[i];
            if (v != 0u && v != 1u) all01 = false;
            if (v != 0u && v != 0x3f800000u) allf = false;
        }
        *flag = all01 ? 0 : (allf ? 2 : 1);
    }
    const int lane = tid & 63, wave = tid >> 6;
    const int gw = blockIdx.x * 4 + wave;
    if (gw < H_ * M_) {
        const int h = gw / M_, m = gw - h * M_;
        float s = 0.f;
        #pragma unroll
        for (int i = 0; i < 3; ++i) {
            int d = lane + i * 64;
            s += wmap[DK_ + d] * Wk[(size_t)(h * DK_ + d) * M_ + m];
        }
        #pragma unroll
        for (int off = 1; off < 64; off <<= 1) s += __shfl_xor(s, off, 64);
        if (lane == 0) wkeff[gw] = s;
    }
    const int gt = blockIdx.x * 256 + tid;
    const int stride = gridDim.x * 256;
    for (int i = gt; i < (M_ + D_) * D_; i += stride) {
        int k = i >> 7, o = i & 127;
        W1t[i] = W1[(size_t)o * (M_ + D_) + k];
    }
    for (int i = gt; i < D_ * D_; i += stride) {
        int k = i >> 7, o = i & 127;
        W2t[i] = W2[(size_t)o * D_ + k];
    }
    for (int i = gt; i < M_ * M_; i += stride) {
        Wvb[i]  = bf1(Wv[i]);
        Wfcb[i] = bf1(Wfc[i]);
    }
}

// ---------------------------------------------------------------- persistent pipelined attention (bf16 skb, NB=4)
__global__ __launch_bounds__(512, 4) void attn_pipe(
    const float* __restrict__ seq, const float* __restrict__ seqE,
    const float* __restrict__ seqT, const void* __restrict__ mask,
    const float* __restrict__ wkeff, const int* __restrict__ flagp,
    unsigned short* __restrict__ ctxb, float* __restrict__ attn_out) {
    __shared__ __hip_bfloat16 skb[N_ * PADROW];   // 50176 B
    __shared__ float slog[H_ * N_];

    const int tid = threadIdx.x;
    const int lane = tid & 63;
    const int j8 = tid & 15;
    const int b0 = blockIdx.x * NB;
    const int flag = *flagp;

    // wkeff in registers
    float wr[2][3][8];
    #pragma unroll
    for (int h = 0; h < 2; ++h)
        #pragma unroll
        for (int t = 0; t < 3; ++t) {
            float4 wa = *(const float4*)&wkeff[h * M_ + t * 128 + j8 * 8];
            float4 wb = *(const float4*)&wkeff[h * M_ + t * 128 + j8 * 8 + 4];
            wr[h][t][0] = wa.x; wr[h][t][1] = wa.y; wr[h][t][2] = wa.z; wr[h][t][3] = wa.w;
            wr[h][t][4] = wb.x; wr[h][t][5] = wb.y; wr[h][t][6] = wb.z; wr[h][t][7] = wb.w;
        }

    float4 pf[12];   // prefetch registers

#define ISSUE(bb) do {                                                        \
    const size_t obase_ = (size_t)(bb) * (N_ * D_);                           \
    _Pragma("unroll")                                                         \
    for (int k2 = 0; k2 < 2; ++k2) {                                          \
        const size_t off_ = obase_ + (size_t)(k2 * 512 + tid) * 8;            \
        pf[k2*6+0] = *(const float4*)&seq [off_];                             \
        pf[k2*6+1] = *(const float4*)&seq [off_ + 4];                         \
        pf[k2*6+2] = *(const float4*)&seqE[off_];                             \
        pf[k2*6+3] = *(const float4*)&seqE[off_ + 4];                         \
        pf[k2*6+4] = *(const float4*)&seqT[off_];                             \
        pf[k2*6+5] = *(const float4*)&seqT[off_ + 4];                         \
    }                                                                         \
    __builtin_amdgcn_sched_barrier(0);  /* pin load issue here */             \
    } while (0)

#define CONSUME() do {                                                        \
    _Pragma("unroll")                                                         \
    for (int k2 = 0; k2 < 2; ++k2) {                                          \
        const int n_ = (k2 * 512 + tid) >> 4;                                 \
        float a0_ = 0.f, a1_ = 0.f;                                           \
        _Pragma("unroll")                                                     \
        for (int t = 0; t < 3; ++t) {                                         \
            float4 v0 = pf[k2*6 + t*2], v1 = pf[k2*6 + t*2 + 1];              \
            a0_ += v0.x*wr[0][t][0] + v0.y*wr[0][t][1] + v0.z*wr[0][t][2]     \
                 + v0.w*wr[0][t][3] + v1.x*wr[0][t][4] + v1.y*wr[0][t][5]     \
                 + v1.z*wr[0][t][6] + v1.w*wr[0][t][7];                       \
            a1_ += v0.x*wr[1][t][0] + v0.y*wr[1][t][1] + v0.z*wr[1][t][2]     \
                 + v0.w*wr[1][t][3] + v1.x*wr[1][t][4] + v1.y*wr[1][t][5]     \
                 + v1.z*wr[1][t][6] + v1.w*wr[1][t][7];                       \
            int4 pk;                                                          \
            pk.x = (int)pk2(v0.x, v0.y); pk.y = (int)pk2(v0.z, v0.w);         \
            pk.z = (int)pk2(v1.x, v1.y); pk.w = (int)pk2(v1.z, v1.w);         \
            *(int4*)&skb[n_ * PADROW + t * 128 + j8 * 8] = pk;                \
        }                                                                     \
        _Pragma("unroll")                                                     \
        for (int off = 1; off < 16; off <<= 1) {                              \
            a0_ += __shfl_xor(a0_, off, 64);                                  \
            a1_ += __shfl_xor(a1_, off, 64);                                  \
        }                                                                     \
        if ((lane & 15) == 0) { slog[n_] = a0_; slog[64 + n_] = a1_; }        \
    } } while (0)

    // prologue
    ISSUE(b0);
    CONSUME();
    __syncthreads();

    for (int bi = 0; bi < NB; ++bi) {
        const int b = b0 + bi;

        if (bi + 1 < NB) ISSUE(b + 1);   // loads fly across softmax+ctx

        // softmax: wave0 h=0, wave1 h=1, lane=n
        if (tid < H_ * N_) {
            const int h = tid >> 6, n = tid & 63;
            float lg = slog[tid];
            int mv;
            if (flag == 0)      mv = ((const int*)mask)[(size_t)b * N_ + n];
            else if (flag == 1) mv = ((const unsigned char*)mask)[(size_t)b * N_ + n];
            else                mv = (((const unsigned int*)mask)[(size_t)b * N_ + n] != 0u) ? 1 : 0;
            if (mv) lg = -INFINITY;
            float mx = lg;
            #pragma unroll
            for (int off = 32; off > 0; off >>= 1) mx = fmaxf(mx, __shfl_xor(mx, off, 64));
            float e = __expf(lg - mx);
            float s = e;
            #pragma unroll
            for (int off = 32; off > 0; off >>= 1) s += __shfl_xor(s, off, 64);
            float a = e / s;
            slog[tid] = a;
            attn_out[((size_t)h * B_ + b) * N_ + n] = a;
        }
        __syncthreads();

        // ctx: 384 threads, bf16 b128 reads (zero-conflict layout from r3)
        if (tid < 384) {
            const int u = tid >> 2, q = tid & 3;
            const int h = (u >= 48) ? 1 : 0;
            const int m8 = u - h * 48;
            const float* pr = &slog[h * 64];
            float acc[8] = {};
            #pragma unroll
            for (int i = 0; i < 16; ++i) {
                const int n = q * 16 + ((i + q * 4) & 15);
                const float a = pr[n];
                int4 kv = *(const int4*)&skb[n * PADROW + m8 * 8];
                acc[0] += a * bflo(kv.x); acc[1] += a * bfhi(kv.x);
                acc[2] += a * bflo(kv.y); acc[3] += a * bfhi(kv.y);
                acc[4] += a * bflo(kv.z); acc[5] += a * bfhi(kv.z);
                acc[6] += a * bflo(kv.w); acc[7] += a * bfhi(kv.w);
            }
            #pragma unroll
            for (int off = 1; off < 4; off <<= 1)
                #pragma unroll
                for (int j = 0; j < 8; ++j) acc[j] += __shfl_xor(acc[j], off, 64);
            if (q == 0) {
                int4 pk;
                pk.x = (int)pk2(acc[0], acc[1]); pk.y = (int)pk2(acc[2], acc[3]);
                pk.z = (int)pk2(acc[4], acc[5]); pk.w = (int)pk2(acc[6], acc[7]);
                *(int4*)&ctxb[(size_t)b * (H_ * M_) + h * M_ + m8 * 8] = pk;
            }
        }
        __syncthreads();

        if (bi + 1 < NB) CONSUME();
        __syncthreads();
    }
#undef ISSUE
#undef CONSUME
}

// ---------------------------------------------------------------- MFMA GEMM: outv = ctx_h @ Wv_h^T (bf16, no LDS)
__global__ __launch_bounds__(256) void gemm_v_mfma(
    const unsigned short* __restrict__ ctxb, const unsigned short* __restrict__ Wvb,
    unsigned short* __restrict__ outvb) {
    const int tid = threadIdx.x;
    const int wave = tid >> 6, lane = tid & 63;
    const int i0 = blockIdx.x * 64;
    const int j0 = blockIdx.y * 64;
    const int aOff = (j0 >= DK_) ? M_ : 0;
    const int r0 = i0 + wave * 16;
    const int lr = lane & 15, lk = (lane >> 4) * 8;
    f32x4 acc[4] = {{0,0,0,0},{0,0,0,0},{0,0,0,0},{0,0,0,0}};
    const unsigned short* arow = &ctxb[(size_t)(r0 + lr) * (H_ * M_) + aOff + lk];
    #pragma unroll
    for (int kk = 0; kk < M_; kk += 32) {
        bf16x8 af = *(const bf16x8*)&arow[kk];
        #pragma unroll
        for (int jn = 0; jn < 4; ++jn) {
            bf16x8 bfr = *(const bf16x8*)&Wvb[(size_t)(j0 + jn * 16 + lr) * M_ + kk + lk];
            acc[jn] = __builtin_amdgcn_mfma_f32_16x16x32_bf16(af, bfr, acc[jn], 0, 0, 0);
        }
    }
    // C: col = lane&15, row = (lane>>4)*4 + q
    #pragma unroll
    for (int jn = 0; jn < 4; ++jn)
        #pragma unroll
        for (int q = 0; q < 4; ++q) {
            int row = r0 + (lane >> 4) * 4 + q;
            outvb[(size_t)row * M_ + j0 + jn * 16 + lr] = bf1(acc[jn][q]);
        }
}

// ---------------------------------------------------------------- MFMA GEMM: fc + leaky + residual (bf16 in, f32 out)
__global__ __launch_bounds__(256) void gemm_fc_mfma(
    const unsigned short* __restrict__ outvb, const unsigned short* __restrict__ Wfcb,
    const float* __restrict__ bfc,
    const float* __restrict__ src, const float* __restrict__ src_s, const float* __restrict__ src_t,
    float* __restrict__ rws) {
    const int tid = threadIdx.x;
    const int wave = tid >> 6, lane = tid & 63;
    const int i0 = blockIdx.x * 64;
    const int j0 = blockIdx.y * 64;
    const int r0 = i0 + wave * 16;
    const int lr = lane & 15, lk = (lane >> 4) * 8;
    f32x4 acc[4] = {{0,0,0,0},{0,0,0,0},{0,0,0,0},{0,0,0,0}};
    const unsigned short* arow = &outvb[(size_t)(r0 + lr) * M_ + lk];
    #pragma unroll
    for (int kk = 0; kk < M_; kk += 32) {
        bf16x8 af = *(const bf16x8*)&arow[kk];
        #pragma unroll
        for (int jn = 0; jn < 4; ++jn) {
            bf16x8 bfr = *(const bf16x8*)&Wfcb[(size_t)(j0 + jn * 16 + lr) * M_ + kk + lk];
            acc[jn] = __builtin_amdgcn_mfma_f32_16x16x32_bf16(af, bfr, acc[jn], 0, 0, 0);
        }
    }
    const float* qsrc = (j0 < D_) ? src : (j0 < 2 * D_) ? src_s : src_t;
    const int joff = j0 % D_;
    #pragma unroll
    for (int jn = 0; jn < 4; ++jn)
        #pragma unroll
        for (int q = 0; q < 4; ++q) {
            int row = r0 + (lane >> 4) * 4 + q;
            int jc = jn * 16 + lr;
            float t = acc[jn][q] + bfc[j0 + jc];
            t = t > 0.f ? t : 0.2f * t;
            t += qsrc[(size_t)row * D_ + joff + jc];
            rws[(size_t)row * M_ + j0 + jc] = t;
        }
}

// ---------------------------------------------------------------- LayerNorm + MLP (8 rows/block, 512 blocks)
__global__ __launch_bounds__(256) void ln_mlp(
    const float* __restrict__ rin, const float* __restrict__ src,
    const float* __restrict__ g, const float* __restrict__ bta,
    const float* __restrict__ W1t, const float* __restrict__ b1,
    const float* __restrict__ W2t, const float* __restrict__ b2,
    float* __restrict__ outp) {
    __shared__ float sa[8 * 520];
    __shared__ float sh[8 * 132];
    const int b0 = blockIdx.x * 8;
    const int tid = threadIdx.x;
    const int row = tid >> 5, part = tid & 31;
    const size_t gr = (size_t)(b0 + row);
    {
        const float* rr = &rin[gr * M_];
        float4 v[3];
        float s = 0.f, sq = 0.f;
        #pragma unroll
        for (int i = 0; i < 3; ++i) {
            v[i] = *(const float4*)&rr[(part + i * 32) * 4];
            s  += v[i].x + v[i].y + v[i].z + v[i].w;
            sq += v[i].x * v[i].x + v[i].y * v[i].y + v[i].z * v[i].z + v[i].w * v[i].w;
        }
        #pragma unroll
        for (int off = 1; off < 32; off <<= 1) {
            s += __shfl_xor(s, off, 64); sq += __shfl_xor(sq, off, 64);
        }
        float mu = s * (1.f / 384.f);
        float rs = rsqrtf(sq * (1.f / 384.f) - mu * mu + 1e-5f);
        #pragma unroll
        for (int i = 0; i < 3; ++i) {
            int k = (part + i * 32) * 4;
            float4 g4 = *(const float4*)&g[k];
            float4 b4 = *(const float4*)&bta[k];
            float4 z;
            z.x = (v[i].x - mu) * rs * g4.x + b4.x;
            z.y = (v[i].y - mu) * rs * g4.y + b4.y;
            z.z = (v[i].z - mu) * rs * g4.z + b4.z;
            z.w = (v[i].w - mu) * rs * g4.w + b4.w;
            *(float4*)&sa[row * 520 + k] = z;
        }
        *(float4*)&sa[row * 520 + M_ + part * 4] = *(const float4*)&src[gr * D_ + part * 4];
    }
    __syncthreads();
    const int c4 = part * 4;
    float acc[4] = {};
    const float* ar = &sa[row * 520];
    #pragma unroll 4
    for (int k4 = 0; k4 < 128; ++k4) {
        float4 a4 = *(const float4*)&ar[k4 * 4];
        #pragma unroll
        for (int j = 0; j < 4; ++j) {
            int k = k4 * 4 + j;
            float a = (j == 0) ? a4.x : (j == 1) ? a4.y : (j == 2) ? a4.z : a4.w;
            float4 w = *(const float4*)&W1t[k * D_ + c4];
            acc[0] += a * w.x; acc[1] += a * w.y; acc[2] += a * w.z; acc[3] += a * w.w;
        }
    }
    {
        float4 bb = *(const float4*)&b1[c4];
        float4 hh;
        hh.x = fmaxf(acc[0] + bb.x, 0.f);
        hh.y = fmaxf(acc[1] + bb.y, 0.f);
        hh.z = fmaxf(acc[2] + bb.z, 0.f);
        hh.w = fmaxf(acc[3] + bb.w, 0.f);
        *(float4*)&sh[row * 132 + c4] = hh;
    }
    __syncthreads();
    float acc2[4] = {};
    const float* hr = &sh[row * 132];
    #pragma unroll 4
    for (int k4 = 0; k4 < 32; ++k4) {
        float4 a4 = *(const float4*)&hr[k4 * 4];
        #pragma unroll
        for (int j = 0; j < 4; ++j) {
            int k = k4 * 4 + j;
            float a = (j == 0) ? a4.x : (j == 1) ? a4.y : (j == 2) ? a4.z : a4.w;
            float4 w = *(const float4*)&W2t[k * D_ + c4];
            acc2[0] += a * w.x; acc2[1] += a * w.y; acc2[2] += a * w.z; acc2[3] += a * w.w;
        }
    }
    float4 bb2 = *(const float4*)&b2[c4];
    float4 oo = make_float4(acc2[0] + bb2.x, acc2[1] + bb2.y, acc2[2] + bb2.z, acc2[3] + bb2.w);
    *(float4*)&outp[gr * D_ + c4] = oo;
}

// ---------------------------------------------------------------- launcher
extern "C" void kernel_launch(void* const* d_in, const int* in_sizes, int n_in,
                              void* d_out, int out_size, void* d_ws, size_t ws_size,
                              hipStream_t stream) {
    (void)in_sizes; (void)n_in; (void)out_size;
    const float* src   = (const float*)d_in[0];
    const float* src_t = (const float*)d_in[1];
    const float* src_s = (const float*)d_in[2];
    const float* seq   = (const float*)d_in[3];
    const float* seq_t = (const float*)d_in[4];
    const float* seq_e = (const float*)d_in[5];
    const void*  mask  = d_in[6];
    // d_in[7] = Wq: unused (cancels in softmax)
    const float* Wk    = (const float*)d_in[8];
    const float* Wv    = (const float*)d_in[9];
    const float* wmap  = (const float*)d_in[10];
    const float* Wfc   = (const float*)d_in[11];
    const float* bfc   = (const float*)d_in[12];
    const float* ln_g  = (const float*)d_in[13];
    const float* ln_b  = (const float*)d_in[14];
    const float* W1    = (const float*)d_in[15];
    const float* b1    = (const float*)d_in[16];
    const float* W2    = (const float*)d_in[17];
    const float* b2    = (const float*)d_in[18];

    if (ws_size < (size_t)WS_TOTAL * sizeof(float)) return;
    float* wsf   = (float*)d_ws;
    int*   flagp = (int*)d_ws;
    float* wkeff = wsf + WS_WKEFF;
    float* W1t   = wsf + WS_W1T;
    float* W2t   = wsf + WS_W2T;
    unsigned short* Wvb   = (unsigned short*)(wsf + WS_WVB);
    unsigned short* Wfcb  = (unsigned short*)(wsf + WS_WFCB);
    unsigned short* ctxb  = (unsigned short*)(wsf + WS_CTXB);
    unsigned short* outvb = (unsigned short*)(wsf + WS_OUTVB);
    float* rws   = wsf + WS_R;
    float* outp     = (float*)d_out;
    float* attn_out = outp + (size_t)B_ * D_;

    prep2<<<256, 256, 0, stream>>>(Wk, wmap, W1, W2, Wv, Wfc, mask, flagp,
                                   wkeff, W1t, W2t, Wvb, Wfcb);
    attn_pipe<<<B_ / NB, 512, 0, stream>>>(seq, seq_e, seq_t, mask, wkeff, flagp, ctxb, attn_out);
    gemm_v_mfma<<<dim3(64, 6), 256, 0, stream>>>(ctxb, Wvb, outvb);
    gemm_fc_mfma<<<dim3(64, 6), 256, 0, stream>>>(outvb, Wfcb, bfc, src, src_s, src_t, rws);
    ln_mlp<<<512, 256, 0, stream>>>(rws, src, ln_g, ln_b, W1t, b1, W2t, b2, outp);
}

// Round 6
// 215.786 us; speedup vs baseline: 2.2415x; 2.2415x over previous
//
#include <hip/hip_runtime.h>
#include <hip/hip_bf16.h>

#define B_ 4096
#define N_ 64
#define D_ 128
#define H_ 2
#define M_ 384
#define DK_ 192
#define NB 8
#define PADROW 392   // bf16 row stride (r3-verified zero-conflict)

// ws float offsets
#define WS_WKEFF 64
#define WS_W1T   1024
#define WS_W2T   66560
#define WS_WVB   82944                      // 147456 ushort = 73728 f32 slots
#define WS_WFCB  156672                     // 147456 ushort
#define WS_CTXB  230400                     // 4096*768 ushort = 1572864 f32 slots
#define WS_OUTVB 1803264                    // 4096*384 ushort = 786432 f32 slots
#define WS_R     2589696                    // 4096*384 f32
#define WS_TOTAL 4162560

typedef __attribute__((ext_vector_type(8))) short bf16x8;
typedef __attribute__((ext_vector_type(4))) float f32x4;

__device__ __forceinline__ unsigned pk2(float a, float b) {
    __hip_bfloat16 x = __float2bfloat16(a), y = __float2bfloat16(b);
    unsigned short ux = __builtin_bit_cast(unsigned short, x);
    unsigned short uy = __builtin_bit_cast(unsigned short, y);
    return (unsigned)ux | ((unsigned)uy << 16);
}
__device__ __forceinline__ float bflo(int v) { return __builtin_bit_cast(float, (unsigned)v << 16); }
__device__ __forceinline__ float bfhi(int v) { return __builtin_bit_cast(float, (unsigned)v & 0xffff0000u); }
__device__ __forceinline__ unsigned short bf1(float a) {
    return __builtin_bit_cast(unsigned short, __float2bfloat16(a));
}

// ---------------------------------------------------------------- prep: mask probe + wk_eff + W1^T/W2^T + bf16 packs
__global__ __launch_bounds__(256) void prep2(
    const float* __restrict__ Wk, const float* __restrict__ wmap,
    const float* __restrict__ W1, const float* __restrict__ W2,
    const float* __restrict__ Wv, const float* __restrict__ Wfc,
    const void* __restrict__ mask, int* __restrict__ flag,
    float* __restrict__ wkeff, float* __restrict__ W1t, float* __restrict__ W2t,
    unsigned short* __restrict__ Wvb, unsigned short* __restrict__ Wfcb) {
    const int tid = threadIdx.x;
    if (blockIdx.x == 0 && tid == 0) {
        const unsigned int* u = (const unsigned int*)mask;
        bool all01 = true, allf = true;
        for (int i = 0; i < 64; ++i) {
            unsigned int v = u[i];
            if (v != 0u && v != 1u) all01 = false;
            if (v != 0u && v != 0x3f800000u) allf = false;
        }
        *flag = all01 ? 0 : (allf ? 2 : 1);
    }
    const int lane = tid & 63, wave = tid >> 6;
    const int gw = blockIdx.x * 4 + wave;
    if (gw < H_ * M_) {
        const int h = gw / M_, m = gw - h * M_;
        float s = 0.f;
        #pragma unroll
        for (int i = 0; i < 3; ++i) {
            int d = lane + i * 64;
            s += wmap[DK_ + d] * Wk[(size_t)(h * DK_ + d) * M_ + m];
        }
        #pragma unroll
        for (int off = 1; off < 64; off <<= 1) s += __shfl_xor(s, off, 64);
        if (lane == 0) wkeff[gw] = s;
    }
    const int gt = blockIdx.x * 256 + tid;
    const int stride = gridDim.x * 256;
    for (int i = gt; i < (M_ + D_) * D_; i += stride) {
        int k = i >> 7, o = i & 127;
        W1t[i] = W1[(size_t)o * (M_ + D_) + k];
    }
    for (int i = gt; i < D_ * D_; i += stride) {
        int k = i >> 7, o = i & 127;
        W2t[i] = W2[(size_t)o * D_ + k];
    }
    for (int i = gt; i < M_ * M_; i += stride) {
        Wvb[i]  = bf1(Wv[i]);
        Wfcb[i] = bf1(Wfc[i]);
    }
}

// ---------------------------------------------------------------- persistent pipelined attention (bf16 skb, NB=8)
__global__ __launch_bounds__(512) void attn_pipe(
    const float* __restrict__ seq, const float* __restrict__ seqE,
    const float* __restrict__ seqT, const void* __restrict__ mask,
    const float* __restrict__ wkeff, const int* __restrict__ flagp,
    unsigned short* __restrict__ ctxb, float* __restrict__ attn_out) {
    __shared__ __hip_bfloat16 skb[N_ * PADROW];   // 50176 B
    __shared__ float slog[H_ * N_];

    const int tid = threadIdx.x;
    const int lane = tid & 63;
    const int j8 = tid & 15;
    const int b0 = blockIdx.x * NB;
    const int flag = *flagp;

    // wkeff in registers
    float wr[2][3][8];
    #pragma unroll
    for (int h = 0; h < 2; ++h)
        #pragma unroll
        for (int t = 0; t < 3; ++t) {
            float4 wa = *(const float4*)&wkeff[h * M_ + t * 128 + j8 * 8];
            float4 wb = *(const float4*)&wkeff[h * M_ + t * 128 + j8 * 8 + 4];
            wr[h][t][0] = wa.x; wr[h][t][1] = wa.y; wr[h][t][2] = wa.z; wr[h][t][3] = wa.w;
            wr[h][t][4] = wb.x; wr[h][t][5] = wb.y; wr[h][t][6] = wb.z; wr[h][t][7] = wb.w;
        }

    float4 pf[12];   // prefetch registers

#define ISSUE(bb) do {                                                        \
    const size_t obase_ = (size_t)(bb) * (N_ * D_);                           \
    _Pragma("unroll")                                                         \
    for (int k2 = 0; k2 < 2; ++k2) {                                          \
        const size_t off_ = obase_ + (size_t)(k2 * 512 + tid) * 8;            \
        pf[k2*6+0] = *(const float4*)&seq [off_];                             \
        pf[k2*6+1] = *(const float4*)&seq [off_ + 4];                         \
        pf[k2*6+2] = *(const float4*)&seqE[off_];                             \
        pf[k2*6+3] = *(const float4*)&seqE[off_ + 4];                         \
        pf[k2*6+4] = *(const float4*)&seqT[off_];                             \
        pf[k2*6+5] = *(const float4*)&seqT[off_ + 4];                         \
    }                                                                         \
    __builtin_amdgcn_sched_barrier(0);  /* pin load issue here */             \
    } while (0)

#define CONSUME() do {                                                        \
    _Pragma("unroll")                                                         \
    for (int k2 = 0; k2 < 2; ++k2) {                                          \
        const int n_ = (k2 * 512 + tid) >> 4;                                 \
        float a0_ = 0.f, a1_ = 0.f;                                           \
        _Pragma("unroll")                                                     \
        for (int t = 0; t < 3; ++t) {                                         \
            float4 v0 = pf[k2*6 + t*2], v1 = pf[k2*6 + t*2 + 1];              \
            a0_ += v0.x*wr[0][t][0] + v0.y*wr[0][t][1] + v0.z*wr[0][t][2]     \
                 + v0.w*wr[0][t][3] + v1.x*wr[0][t][4] + v1.y*wr[0][t][5]     \
                 + v1.z*wr[0][t][6] + v1.w*wr[0][t][7];                       \
            a1_ += v0.x*wr[1][t][0] + v0.y*wr[1][t][1] + v0.z*wr[1][t][2]     \
                 + v0.w*wr[1][t][3] + v1.x*wr[1][t][4] + v1.y*wr[1][t][5]     \
                 + v1.z*wr[1][t][6] + v1.w*wr[1][t][7];                       \
            int4 pk;                                                          \
            pk.x = (int)pk2(v0.x, v0.y); pk.y = (int)pk2(v0.z, v0.w);         \
            pk.z = (int)pk2(v1.x, v1.y); pk.w = (int)pk2(v1.z, v1.w);         \
            *(int4*)&skb[n_ * PADROW + t * 128 + j8 * 8] = pk;                \
        }                                                                     \
        _Pragma("unroll")                                                     \
        for (int off = 1; off < 16; off <<= 1) {                              \
            a0_ += __shfl_xor(a0_, off, 64);                                  \
            a1_ += __shfl_xor(a1_, off, 64);                                  \
        }                                                                     \
        if ((lane & 15) == 0) { slog[n_] = a0_; slog[64 + n_] = a1_; }        \
    } } while (0)

    // prologue
    ISSUE(b0);
    CONSUME();
    __syncthreads();

    for (int bi = 0; bi < NB; ++bi) {
        const int b = b0 + bi;

        if (bi + 1 < NB) ISSUE(b + 1);   // loads fly across softmax+ctx

        // softmax: wave0 h=0, wave1 h=1, lane=n
        if (tid < H_ * N_) {
            const int h = tid >> 6, n = tid & 63;
            float lg = slog[tid];
            int mv;
            if (flag == 0)      mv = ((const int*)mask)[(size_t)b * N_ + n];
            else if (flag == 1) mv = ((const unsigned char*)mask)[(size_t)b * N_ + n];
            else                mv = (((const unsigned int*)mask)[(size_t)b * N_ + n] != 0u) ? 1 : 0;
            if (mv) lg = -INFINITY;
            float mx = lg;
            #pragma unroll
            for (int off = 32; off > 0; off >>= 1) mx = fmaxf(mx, __shfl_xor(mx, off, 64));
            float e = __expf(lg - mx);
            float s = e;
            #pragma unroll
            for (int off = 32; off > 0; off >>= 1) s += __shfl_xor(s, off, 64);
            float a = e / s;
            slog[tid] = a;
            attn_out[((size_t)h * B_ + b) * N_ + n] = a;
        }
        __syncthreads();

        // ctx: 384 threads, bf16 b128 reads (zero-conflict layout from r3)
        if (tid < 384) {
            const int u = tid >> 2, q = tid & 3;
            const int h = (u >= 48) ? 1 : 0;
            const int m8 = u - h * 48;
            const float* pr = &slog[h * 64];
            float acc[8] = {};
            #pragma unroll
            for (int i = 0; i < 16; ++i) {
                const int n = q * 16 + ((i + q * 4) & 15);
                const float a = pr[n];
                int4 kv = *(const int4*)&skb[n * PADROW + m8 * 8];
                acc[0] += a * bflo(kv.x); acc[1] += a * bfhi(kv.x);
                acc[2] += a * bflo(kv.y); acc[3] += a * bfhi(kv.y);
                acc[4] += a * bflo(kv.z); acc[5] += a * bfhi(kv.z);
                acc[6] += a * bflo(kv.w); acc[7] += a * bfhi(kv.w);
            }
            #pragma unroll
            for (int off = 1; off < 4; off <<= 1)
                #pragma unroll
                for (int j = 0; j < 8; ++j) acc[j] += __shfl_xor(acc[j], off, 64);
            if (q == 0) {
                int4 pk;
                pk.x = (int)pk2(acc[0], acc[1]); pk.y = (int)pk2(acc[2], acc[3]);
                pk.z = (int)pk2(acc[4], acc[5]); pk.w = (int)pk2(acc[6], acc[7]);
                *(int4*)&ctxb[(size_t)b * (H_ * M_) + h * M_ + m8 * 8] = pk;
            }
        }
        __syncthreads();

        if (bi + 1 < NB) CONSUME();
        __syncthreads();
    }
#undef ISSUE
#undef CONSUME
}

// ---------------------------------------------------------------- MFMA GEMM: outv = ctx_h @ Wv_h^T (bf16, no LDS)
__global__ __launch_bounds__(256) void gemm_v_mfma(
    const unsigned short* __restrict__ ctxb, const unsigned short* __restrict__ Wvb,
    unsigned short* __restrict__ outvb) {
    const int tid = threadIdx.x;
    const int wave = tid >> 6, lane = tid & 63;
    const int i0 = blockIdx.x * 64;
    const int j0 = blockIdx.y * 64;
    const int aOff = (j0 >= DK_) ? M_ : 0;
    const int r0 = i0 + wave * 16;
    const int lr = lane & 15, lk = (lane >> 4) * 8;
    f32x4 acc[4] = {{0,0,0,0},{0,0,0,0},{0,0,0,0},{0,0,0,0}};
    const unsigned short* arow = &ctxb[(size_t)(r0 + lr) * (H_ * M_) + aOff + lk];
    #pragma unroll
    for (int kk = 0; kk < M_; kk += 32) {
        bf16x8 af = *(const bf16x8*)&arow[kk];
        #pragma unroll
        for (int jn = 0; jn < 4; ++jn) {
            bf16x8 bfr = *(const bf16x8*)&Wvb[(size_t)(j0 + jn * 16 + lr) * M_ + kk + lk];
            acc[jn] = __builtin_amdgcn_mfma_f32_16x16x32_bf16(af, bfr, acc[jn], 0, 0, 0);
        }
    }
    // C: col = lane&15, row = (lane>>4)*4 + q
    #pragma unroll
    for (int jn = 0; jn < 4; ++jn)
        #pragma unroll
        for (int q = 0; q < 4; ++q) {
            int row = r0 + (lane >> 4) * 4 + q;
            outvb[(size_t)row * M_ + j0 + jn * 16 + lr] = bf1(acc[jn][q]);
        }
}

// ---------------------------------------------------------------- MFMA GEMM: fc + leaky + residual (bf16 in, f32 out)
__global__ __launch_bounds__(256) void gemm_fc_mfma(
    const unsigned short* __restrict__ outvb, const unsigned short* __restrict__ Wfcb,
    const float* __restrict__ bfc,
    const float* __restrict__ src, const float* __restrict__ src_s, const float* __restrict__ src_t,
    float* __restrict__ rws) {
    const int tid = threadIdx.x;
    const int wave = tid >> 6, lane = tid & 63;
    const int i0 = blockIdx.x * 64;
    const int j0 = blockIdx.y * 64;
    const int r0 = i0 + wave * 16;
    const int lr = lane & 15, lk = (lane >> 4) * 8;
    f32x4 acc[4] = {{0,0,0,0},{0,0,0,0},{0,0,0,0},{0,0,0,0}};
    const unsigned short* arow = &outvb[(size_t)(r0 + lr) * M_ + lk];
    #pragma unroll
    for (int kk = 0; kk < M_; kk += 32) {
        bf16x8 af = *(const bf16x8*)&arow[kk];
        #pragma unroll
        for (int jn = 0; jn < 4; ++jn) {
            bf16x8 bfr = *(const bf16x8*)&Wfcb[(size_t)(j0 + jn * 16 + lr) * M_ + kk + lk];
            acc[jn] = __builtin_amdgcn_mfma_f32_16x16x32_bf16(af, bfr, acc[jn], 0, 0, 0);
        }
    }
    const float* qsrc = (j0 < D_) ? src : (j0 < 2 * D_) ? src_s : src_t;
    const int joff = j0 % D_;
    #pragma unroll
    for (int jn = 0; jn < 4; ++jn)
        #pragma unroll
        for (int q = 0; q < 4; ++q) {
            int row = r0 + (lane >> 4) * 4 + q;
            int jc = jn * 16 + lr;
            float t = acc[jn][q] + bfc[j0 + jc];
            t = t > 0.f ? t : 0.2f * t;
            t += qsrc[(size_t)row * D_ + joff + jc];
            rws[(size_t)row * M_ + j0 + jc] = t;
        }
}

// ---------------------------------------------------------------- LayerNorm + MLP (8 rows/block, 512 blocks)
__global__ __launch_bounds__(256) void ln_mlp(
    const float* __restrict__ rin, const float* __restrict__ src,
    const float* __restrict__ g, const float* __restrict__ bta,
    const float* __restrict__ W1t, const float* __restrict__ b1,
    const float* __restrict__ W2t, const float* __restrict__ b2,
    float* __restrict__ outp) {
    __shared__ float sa[8 * 520];
    __shared__ float sh[8 * 132];
    const int b0 = blockIdx.x * 8;
    const int tid = threadIdx.x;
    const int row = tid >> 5, part = tid & 31;
    const size_t gr = (size_t)(b0 + row);
    {
        const float* rr = &rin[gr * M_];
        float4 v[3];
        float s = 0.f, sq = 0.f;
        #pragma unroll
        for (int i = 0; i < 3; ++i) {
            v[i] = *(const float4*)&rr[(part + i * 32) * 4];
            s  += v[i].x + v[i].y + v[i].z + v[i].w;
            sq += v[i].x * v[i].x + v[i].y * v[i].y + v[i].z * v[i].z + v[i].w * v[i].w;
        }
        #pragma unroll
        for (int off = 1; off < 32; off <<= 1) {
            s += __shfl_xor(s, off, 64); sq += __shfl_xor(sq, off, 64);
        }
        float mu = s * (1.f / 384.f);
        float rs = rsqrtf(sq * (1.f / 384.f) - mu * mu + 1e-5f);
        #pragma unroll
        for (int i = 0; i < 3; ++i) {
            int k = (part + i * 32) * 4;
            float4 g4 = *(const float4*)&g[k];
            float4 b4 = *(const float4*)&bta[k];
            float4 z;
            z.x = (v[i].x - mu) * rs * g4.x + b4.x;
            z.y = (v[i].y - mu) * rs * g4.y + b4.y;
            z.z = (v[i].z - mu) * rs * g4.z + b4.z;
            z.w = (v[i].w - mu) * rs * g4.w + b4.w;
            *(float4*)&sa[row * 520 + k] = z;
        }
        *(float4*)&sa[row * 520 + M_ + part * 4] = *(const float4*)&src[gr * D_ + part * 4];
    }
    __syncthreads();
    const int c4 = part * 4;
    float acc[4] = {};
    const float* ar = &sa[row * 520];
    #pragma unroll 4
    for (int k4 = 0; k4 < 128; ++k4) {
        float4 a4 = *(const float4*)&ar[k4 * 4];
        #pragma unroll
        for (int j = 0; j < 4; ++j) {
            int k = k4 * 4 + j;
            float a = (j == 0) ? a4.x : (j == 1) ? a4.y : (j == 2) ? a4.z : a4.w;
            float4 w = *(const float4*)&W1t[k * D_ + c4];
            acc[0] += a * w.x; acc[1] += a * w.y; acc[2] += a * w.z; acc[3] += a * w.w;
        }
    }
    {
        float4 bb = *(const float4*)&b1[c4];
        float4 hh;
        hh.x = fmaxf(acc[0] + bb.x, 0.f);
        hh.y = fmaxf(acc[1] + bb.y, 0.f);
        hh.z = fmaxf(acc[2] + bb.z, 0.f);
        hh.w = fmaxf(acc[3] + bb.w, 0.f);
        *(float4*)&sh[row * 132 + c4] = hh;
    }
    __syncthreads();
    float acc2[4] = {};
    const float* hr = &sh[row * 132];
    #pragma unroll 4
    for (int k4 = 0; k4 < 32; ++k4) {
        float4 a4 = *(const float4*)&hr[k4 * 4];
        #pragma unroll
        for (int j = 0; j < 4; ++j) {
            int k = k4 * 4 + j;
            float a = (j == 0) ? a4.x : (j == 1) ? a4.y : (j == 2) ? a4.z : a4.w;
            float4 w = *(const float4*)&W2t[k * D_ + c4];
            acc2[0] += a * w.x; acc2[1] += a * w.y; acc2[2] += a * w.z; acc2[3] += a * w.w;
        }
    }
    float4 bb2 = *(const float4*)&b2[c4];
    float4 oo = make_float4(acc2[0] + bb2.x, acc2[1] + bb2.y, acc2[2] + bb2.z, acc2[3] + bb2.w);
    *(float4*)&outp[gr * D_ + c4] = oo;
}

// ---------------------------------------------------------------- launcher
extern "C" void kernel_launch(void* const* d_in, const int* in_sizes, int n_in,
                              void* d_out, int out_size, void* d_ws, size_t ws_size,
                              hipStream_t stream) {
    (void)in_sizes; (void)n_in; (void)out_size;
    const float* src   = (const float*)d_in[0];
    const float* src_t = (const float*)d_in[1];
    const float* src_s = (const float*)d_in[2];
    const float* seq   = (const float*)d_in[3];
    const float* seq_t = (const float*)d_in[4];
    const float* seq_e = (const float*)d_in[5];
    const void*  mask  = d_in[6];
    // d_in[7] = Wq: unused (cancels in softmax)
    const float* Wk    = (const float*)d_in[8];
    const float* Wv    = (const float*)d_in[9];
    const float* wmap  = (const float*)d_in[10];
    const float* Wfc   = (const float*)d_in[11];
    const float* bfc   = (const float*)d_in[12];
    const float* ln_g  = (const float*)d_in[13];
    const float* ln_b  = (const float*)d_in[14];
    const float* W1    = (const float*)d_in[15];
    const float* b1    = (const float*)d_in[16];
    const float* W2    = (const float*)d_in[17];
    const float* b2    = (const float*)d_in[18];

    if (ws_size < (size_t)WS_TOTAL * sizeof(float)) return;
    float* wsf   = (float*)d_ws;
    int*   flagp = (int*)d_ws;
    float* wkeff = wsf + WS_WKEFF;
    float* W1t   = wsf + WS_W1T;
    float* W2t   = wsf + WS_W2T;
    unsigned short* Wvb   = (unsigned short*)(wsf + WS_WVB);
    unsigned short* Wfcb  = (unsigned short*)(wsf + WS_WFCB);
    unsigned short* ctxb  = (unsigned short*)(wsf + WS_CTXB);
    unsigned short* outvb = (unsigned short*)(wsf + WS_OUTVB);
    float* rws   = wsf + WS_R;
    float* outp     = (float*)d_out;
    float* attn_out = outp + (size_t)B_ * D_;

    prep2<<<256, 256, 0, stream>>>(Wk, wmap, W1, W2, Wv, Wfc, mask, flagp,
                                   wkeff, W1t, W2t, Wvb, Wfcb);
    attn_pipe<<<B_ / NB, 512, 0, stream>>>(seq, seq_e, seq_t, mask, wkeff, flagp, ctxb, attn_out);
    gemm_v_mfma<<<dim3(64, 6), 256, 0, stream>>>(ctxb, Wvb, outvb);
    gemm_fc_mfma<<<dim3(64, 6), 256, 0, stream>>>(outvb, Wfcb, bfc, src, src_s, src_t, rws);
    ln_mlp<<<512, 256, 0, stream>>>(rws, src, ln_g, ln_b, W1t, b1, W2t, b2, outp);
}

// Round 8
// 172.068 us; speedup vs baseline: 2.8110x; 1.2541x over previous
//
#include <hip/hip_runtime.h>
#include <hip/hip_bf16.h>

#define B_ 4096
#define N_ 64
#define D_ 128
#define H_ 2
#define M_ 384
#define DK_ 192
#define PADROW 392   // bf16 row stride (r3/r6-verified zero-conflict)

// ws float offsets
#define WS_W1T   1024
#define WS_W2T   66560
#define WS_WVB   82944                      // 147456 ushort
#define WS_WFCB  156672                     // 147456 ushort
#define WS_CTXB  230400                     // 4096*768 ushort
#define WS_OUTVB 1803264                    // 4096*384 ushort
#define WS_R     2589696                    // 4096*384 f32 (wkp aliases its head: prep->attn only)
#define WS_TOTAL 4162560

typedef __attribute__((ext_vector_type(8))) short bf16x8;
typedef __attribute__((ext_vector_type(4))) float f32x4;

__device__ __forceinline__ unsigned pk2(float a, float b) {
    __hip_bfloat16 x = __float2bfloat16(a), y = __float2bfloat16(b);
    unsigned short ux = __builtin_bit_cast(unsigned short, x);
    unsigned short uy = __builtin_bit_cast(unsigned short, y);
    return (unsigned)ux | ((unsigned)uy << 16);
}
__device__ __forceinline__ float bflo(int v) { return __builtin_bit_cast(float, (unsigned)v << 16); }
__device__ __forceinline__ float bfhi(int v) { return __builtin_bit_cast(float, (unsigned)v & 0xffff0000u); }
__device__ __forceinline__ unsigned short bf1(float a) {
    return __builtin_bit_cast(unsigned short, __float2bfloat16(a));
}

// ---------------------------------------------------------------- prep: mask probe + wkp (bf16 padded) + W1^T/W2^T + bf16 packs
__global__ __launch_bounds__(256) void prep2(
    const float* __restrict__ Wk, const float* __restrict__ wmap,
    const float* __restrict__ W1, const float* __restrict__ W2,
    const float* __restrict__ Wv, const float* __restrict__ Wfc,
    const void* __restrict__ mask, int* __restrict__ flag,
    unsigned short* __restrict__ wkp, float* __restrict__ W1t, float* __restrict__ W2t,
    unsigned short* __restrict__ Wvb, unsigned short* __restrict__ Wfcb) {
    const int tid = threadIdx.x;
    if (blockIdx.x == 0 && tid == 0) {
        const unsigned int* u = (const unsigned int*)mask;
        bool all01 = true, allf = true;
        for (int i = 0; i < 64; ++i) {
            unsigned int v = u[i];
            if (v != 0u && v != 1u) all01 = false;
            if (v != 0u && v != 0x3f800000u) allf = false;
        }
        *flag = all01 ? 0 : (allf ? 2 : 1);
    }
    const int lane = tid & 63, wave = tid >> 6;
    const int gw = blockIdx.x * 4 + wave;
    if (gw < H_ * M_) {   // wkeff[h][m] = sum_d w2[d] * Wk[h*DK+d][m], stored bf16 padded to 16 rows
        const int h = gw / M_, m = gw - h * M_;
        float s = 0.f;
        #pragma unroll
        for (int i = 0; i < 3; ++i) {
            int d = lane + i * 64;
            s += wmap[DK_ + d] * Wk[(size_t)(h * DK_ + d) * M_ + m];
        }
        #pragma unroll
        for (int off = 1; off < 64; off <<= 1) s += __shfl_xor(s, off, 64);
        if (lane == 0) wkp[gw] = bf1(s);
    }
    const int gt = blockIdx.x * 256 + tid;
    const int stride = gridDim.x * 256;
    for (int i = gt + H_ * M_; i < 16 * M_; i += stride) wkp[i] = 0;   // pad rows 2..15
    for (int i = gt; i < (M_ + D_) * D_; i += stride) {
        int k = i >> 7, o = i & 127;
        W1t[i] = W1[(size_t)o * (M_ + D_) + k];
    }
    for (int i = gt; i < D_ * D_; i += stride) {
        int k = i >> 7, o = i & 127;
        W2t[i] = W2[(size_t)o * D_ + k];
    }
    for (int i = gt; i < M_ * M_; i += stride) {
        Wvb[i]  = bf1(Wv[i]);
        Wfcb[i] = bf1(Wfc[i]);
    }
}

// ---------------------------------------------------------------- attention v3: stage -> MFMA logits -> softmax -> ctx
__global__ __launch_bounds__(512) void attn_v3(
    const float* __restrict__ seq, const float* __restrict__ seqE,
    const float* __restrict__ seqT, const void* __restrict__ mask,
    const unsigned short* __restrict__ wkp, const int* __restrict__ flagp,
    unsigned short* __restrict__ ctxb, float* __restrict__ attn_out) {
    __shared__ __hip_bfloat16 skb[N_ * PADROW];   // 50176 B
    __shared__ float slog[H_ * N_];

    const int b = blockIdx.x;
    const int tid = threadIdx.x;
    const int lane = tid & 63;
    const int wave = tid >> 6;
    const int j8 = tid & 15;

    // ---- P1: pure staging, f32 -> bf16 LDS (b128 writes)
    const float* base0 = seq  + (size_t)b * (N_ * D_);
    const float* base1 = seqE + (size_t)b * (N_ * D_);
    const float* base2 = seqT + (size_t)b * (N_ * D_);
    #pragma unroll
    for (int k2 = 0; k2 < 2; ++k2) {
        const int idx8 = k2 * 512 + tid;
        const int n = idx8 >> 4;
        const size_t off = (size_t)idx8 * 8;
        #pragma unroll
        for (int t = 0; t < 3; ++t) {
            const float* bp = (t == 0) ? base0 : (t == 1) ? base1 : base2;
            float4 v0 = *(const float4*)&bp[off];
            float4 v1 = *(const float4*)&bp[off + 4];
            int4 pk;
            pk.x = (int)pk2(v0.x, v0.y); pk.y = (int)pk2(v0.z, v0.w);
            pk.z = (int)pk2(v1.x, v1.y); pk.w = (int)pk2(v1.z, v1.w);
            *(int4*)&skb[n * PADROW + t * 128 + j8 * 8] = pk;
        }
    }
    __syncthreads();

    // ---- P2: logits via MFMA. Wave w computes n-tile w (rows w*16..+16), cols = heads (only 0,1 kept).
    if (wave < 4) {
        const int lr = lane & 15, lk = (lane >> 4) * 8;
        f32x4 acc = {0.f, 0.f, 0.f, 0.f};
        const __hip_bfloat16* arow = &skb[(wave * 16 + lr) * PADROW + lk];
        const unsigned short* brow = &wkp[lr * M_ + lk];
        #pragma unroll
        for (int s = 0; s < 12; ++s) {
            bf16x8 af = *(const bf16x8*)&arow[s * 32];
            bf16x8 bfr = *(const bf16x8*)&brow[s * 32];
            acc = __builtin_amdgcn_mfma_f32_16x16x32_bf16(af, bfr, acc, 0, 0, 0);
        }
        if (lr < 2) {   // C: col(lane&15)=h, row=(lane>>4)*4+q = n within tile
            #pragma unroll
            for (int q = 0; q < 4; ++q)
                slog[lr * 64 + wave * 16 + (lane >> 4) * 4 + q] = acc[q];
        }
    }
    __syncthreads();

    // ---- P3: mask + softmax (2 waves), write attn_out
    if (tid < H_ * N_) {
        const int h = tid >> 6, n = tid & 63;
        float lg = slog[tid];
        const int flag = *flagp;
        int mv;
        if (flag == 0)      mv = ((const int*)mask)[(size_t)b * N_ + n];
        else if (flag == 1) mv = ((const unsigned char*)mask)[(size_t)b * N_ + n];
        else                mv = (((const unsigned int*)mask)[(size_t)b * N_ + n] != 0u) ? 1 : 0;
        if (mv) lg = -INFINITY;
        float mx = lg;
        #pragma unroll
        for (int off = 32; off > 0; off >>= 1) mx = fmaxf(mx, __shfl_xor(mx, off, 64));
        float e = __expf(lg - mx);
        float s = e;
        #pragma unroll
        for (int off = 32; off > 0; off >>= 1) s += __shfl_xor(s, off, 64);
        float a = e / s;
        slog[tid] = a;
        attn_out[((size_t)h * B_ + b) * N_ + n] = a;
    }
    __syncthreads();

    // ---- P4: ctx[h][m] = sum_n p[h][n]*k[n][m]; 384 threads, b128 reads, 4-way n split (0-conflict skew)
    if (tid < 384) {
        const int u = tid >> 2, q = tid & 3;
        const int h = (u >= 48) ? 1 : 0;
        const int m8 = u - h * 48;
        const float* pr = &slog[h * 64];
        float acc[8] = {};
        #pragma unroll
        for (int i = 0; i < 16; ++i) {
            const int n = q * 16 + ((i + q * 4) & 15);
            const float a = pr[n];
            int4 kv = *(const int4*)&skb[n * PADROW + m8 * 8];
            acc[0] += a * bflo(kv.x); acc[1] += a * bfhi(kv.x);
            acc[2] += a * bflo(kv.y); acc[3] += a * bfhi(kv.y);
            acc[4] += a * bflo(kv.z); acc[5] += a * bfhi(kv.z);
            acc[6] += a * bflo(kv.w); acc[7] += a * bfhi(kv.w);
        }
        #pragma unroll
        for (int off = 1; off < 4; off <<= 1)
            #pragma unroll
            for (int j = 0; j < 8; ++j) acc[j] += __shfl_xor(acc[j], off, 64);
        if (q == 0) {
            int4 pk;
            pk.x = (int)pk2(acc[0], acc[1]); pk.y = (int)pk2(acc[2], acc[3]);
            pk.z = (int)pk2(acc[4], acc[5]); pk.w = (int)pk2(acc[6], acc[7]);
            *(int4*)&ctxb[(size_t)b * (H_ * M_) + h * M_ + m8 * 8] = pk;
        }
    }
}

// ---------------------------------------------------------------- MFMA GEMM: outv = ctx_h @ Wv_h^T (bf16, no LDS)
__global__ __launch_bounds__(256) void gemm_v_mfma(
    const unsigned short* __restrict__ ctxb, const unsigned short* __restrict__ Wvb,
    unsigned short* __restrict__ outvb) {
    const int tid = threadIdx.x;
    const int wave = tid >> 6, lane = tid & 63;
    const int i0 = blockIdx.x * 64;
    const int j0 = blockIdx.y * 64;
    const int aOff = (j0 >= DK_) ? M_ : 0;
    const int r0 = i0 + wave * 16;
    const int lr = lane & 15, lk = (lane >> 4) * 8;
    f32x4 acc[4] = {{0,0,0,0},{0,0,0,0},{0,0,0,0},{0,0,0,0}};
    const unsigned short* arow = &ctxb[(size_t)(r0 + lr) * (H_ * M_) + aOff + lk];
    #pragma unroll
    for (int kk = 0; kk < M_; kk += 32) {
        bf16x8 af = *(const bf16x8*)&arow[kk];
        #pragma unroll
        for (int jn = 0; jn < 4; ++jn) {
            bf16x8 bfr = *(const bf16x8*)&Wvb[(size_t)(j0 + jn * 16 + lr) * M_ + kk + lk];
            acc[jn] = __builtin_amdgcn_mfma_f32_16x16x32_bf16(af, bfr, acc[jn], 0, 0, 0);
        }
    }
    #pragma unroll
    for (int jn = 0; jn < 4; ++jn)
        #pragma unroll
        for (int q = 0; q < 4; ++q) {
            int row = r0 + (lane >> 4) * 4 + q;
            outvb[(size_t)row * M_ + j0 + jn * 16 + lr] = bf1(acc[jn][q]);
        }
}

// ---------------------------------------------------------------- MFMA GEMM: fc + leaky + residual (bf16 in, f32 out)
__global__ __launch_bounds__(256) void gemm_fc_mfma(
    const unsigned short* __restrict__ outvb, const unsigned short* __restrict__ Wfcb,
    const float* __restrict__ bfc,
    const float* __restrict__ src, const float* __restrict__ src_s, const float* __restrict__ src_t,
    float* __restrict__ rws) {
    const int tid = threadIdx.x;
    const int wave = tid >> 6, lane = tid & 63;
    const int i0 = blockIdx.x * 64;
    const int j0 = blockIdx.y * 64;
    const int r0 = i0 + wave * 16;
    const int lr = lane & 15, lk = (lane >> 4) * 8;
    f32x4 acc[4] = {{0,0,0,0},{0,0,0,0},{0,0,0,0},{0,0,0,0}};
    const unsigned short* arow = &outvb[(size_t)(r0 + lr) * M_ + lk];
    #pragma unroll
    for (int kk = 0; kk < M_; kk += 32) {
        bf16x8 af = *(const bf16x8*)&arow[kk];
        #pragma unroll
        for (int jn = 0; jn < 4; ++jn) {
            bf16x8 bfr = *(const bf16x8*)&Wfcb[(size_t)(j0 + jn * 16 + lr) * M_ + kk + lk];
            acc[jn] = __builtin_amdgcn_mfma_f32_16x16x32_bf16(af, bfr, acc[jn], 0, 0, 0);
        }
    }
    const float* qsrc = (j0 < D_) ? src : (j0 < 2 * D_) ? src_s : src_t;
    const int joff = j0 % D_;
    #pragma unroll
    for (int jn = 0; jn < 4; ++jn)
        #pragma unroll
        for (int q = 0; q < 4; ++q) {
            int row = r0 + (lane >> 4) * 4 + q;
            int jc = jn * 16 + lr;
            float t = acc[jn][q] + bfc[j0 + jc];
            t = t > 0.f ? t : 0.2f * t;
            t += qsrc[(size_t)row * D_ + joff + jc];
            rws[(size_t)row * M_ + j0 + jc] = t;
        }
}

// ---------------------------------------------------------------- LayerNorm + MLP (8 rows/block, 512 blocks)
__global__ __launch_bounds__(256) void ln_mlp(
    const float* __restrict__ rin, const float* __restrict__ src,
    const float* __restrict__ g, const float* __restrict__ bta,
    const float* __restrict__ W1t, const float* __restrict__ b1,
    const float* __restrict__ W2t, const float* __restrict__ b2,
    float* __restrict__ outp) {
    __shared__ float sa[8 * 520];
    __shared__ float sh[8 * 132];
    const int b0 = blockIdx.x * 8;
    const int tid = threadIdx.x;
    const int row = tid >> 5, part = tid & 31;
    const size_t gr = (size_t)(b0 + row);
    {
        const float* rr = &rin[gr * M_];
        float4 v[3];
        float s = 0.f, sq = 0.f;
        #pragma unroll
        for (int i = 0; i < 3; ++i) {
            v[i] = *(const float4*)&rr[(part + i * 32) * 4];
            s  += v[i].x + v[i].y + v[i].z + v[i].w;
            sq += v[i].x * v[i].x + v[i].y * v[i].y + v[i].z * v[i].z + v[i].w * v[i].w;
        }
        #pragma unroll
        for (int off = 1; off < 32; off <<= 1) {
            s += __shfl_xor(s, off, 64); sq += __shfl_xor(sq, off, 64);
        }
        float mu = s * (1.f / 384.f);
        float rs = rsqrtf(sq * (1.f / 384.f) - mu * mu + 1e-5f);
        #pragma unroll
        for (int i = 0; i < 3; ++i) {
            int k = (part + i * 32) * 4;
            float4 g4 = *(const float4*)&g[k];
            float4 b4 = *(const float4*)&bta[k];
            float4 z;
            z.x = (v[i].x - mu) * rs * g4.x + b4.x;
            z.y = (v[i].y - mu) * rs * g4.y + b4.y;
            z.z = (v[i].z - mu) * rs * g4.z + b4.z;
            z.w = (v[i].w - mu) * rs * g4.w + b4.w;
            *(float4*)&sa[row * 520 + k] = z;
        }
        *(float4*)&sa[row * 520 + M_ + part * 4] = *(const float4*)&src[gr * D_ + part * 4];
    }
    __syncthreads();
    const int c4 = part * 4;
    float acc[4] = {};
    const float* ar = &sa[row * 520];
    #pragma unroll 4
    for (int k4 = 0; k4 < 128; ++k4) {
        float4 a4 = *(const float4*)&ar[k4 * 4];
        #pragma unroll
        for (int j = 0; j < 4; ++j) {
            int k = k4 * 4 + j;
            float a = (j == 0) ? a4.x : (j == 1) ? a4.y : (j == 2) ? a4.z : a4.w;
            float4 w = *(const float4*)&W1t[k * D_ + c4];
            acc[0] += a * w.x; acc[1] += a * w.y; acc[2] += a * w.z; acc[3] += a * w.w;
        }
    }
    {
        float4 bb = *(const float4*)&b1[c4];
        float4 hh;
        hh.x = fmaxf(acc[0] + bb.x, 0.f);
        hh.y = fmaxf(acc[1] + bb.y, 0.f);
        hh.z = fmaxf(acc[2] + bb.z, 0.f);
        hh.w = fmaxf(acc[3] + bb.w, 0.f);
        *(float4*)&sh[row * 132 + c4] = hh;
    }
    __syncthreads();
    float acc2[4] = {};
    const float* hr = &sh[row * 132];
    #pragma unroll 4
    for (int k4 = 0; k4 < 32; ++k4) {
        float4 a4 = *(const float4*)&hr[k4 * 4];
        #pragma unroll
        for (int j = 0; j < 4; ++j) {
            int k = k4 * 4 + j;
            float a = (j == 0) ? a4.x : (j == 1) ? a4.y : (j == 2) ? a4.z : a4.w;
            float4 w = *(const float4*)&W2t[k * D_ + c4];
            acc2[0] += a * w.x; acc2[1] += a * w.y; acc2[2] += a * w.z; acc2[3] += a * w.w;
        }
    }
    float4 bb2 = *(const float4*)&b2[c4];
    float4 oo = make_float4(acc2[0] + bb2.x, acc2[1] + bb2.y, acc2[2] + bb2.z, acc2[3] + bb2.w);
    *(float4*)&outp[gr * D_ + c4] = oo;
}

// ---------------------------------------------------------------- launcher
extern "C" void kernel_launch(void* const* d_in, const int* in_sizes, int n_in,
                              void* d_out, int out_size, void* d_ws, size_t ws_size,
                              hipStream_t stream) {
    (void)in_sizes; (void)n_in; (void)out_size;
    const float* src   = (const float*)d_in[0];
    const float* src_t = (const float*)d_in[1];
    const float* src_s = (const float*)d_in[2];
    const float* seq   = (const float*)d_in[3];
    const float* seq_t = (const float*)d_in[4];
    const float* seq_e = (const float*)d_in[5];
    const void*  mask  = d_in[6];
    // d_in[7] = Wq: unused (cancels in softmax)
    const float* Wk    = (const float*)d_in[8];
    const float* Wv    = (const float*)d_in[9];
    const float* wmap  = (const float*)d_in[10];
    const float* Wfc   = (const float*)d_in[11];
    const float* bfc   = (const float*)d_in[12];
    const float* ln_g  = (const float*)d_in[13];
    const float* ln_b  = (const float*)d_in[14];
    const float* W1    = (const float*)d_in[15];
    const float* b1    = (const float*)d_in[16];
    const float* W2    = (const float*)d_in[17];
    const float* b2    = (const float*)d_in[18];

    if (ws_size < (size_t)WS_TOTAL * sizeof(float)) return;
    float* wsf   = (float*)d_ws;
    int*   flagp = (int*)d_ws;
    float* W1t   = wsf + WS_W1T;
    float* W2t   = wsf + WS_W2T;
    unsigned short* Wvb   = (unsigned short*)(wsf + WS_WVB);
    unsigned short* Wfcb  = (unsigned short*)(wsf + WS_WFCB);
    unsigned short* ctxb  = (unsigned short*)(wsf + WS_CTXB);
    unsigned short* outvb = (unsigned short*)(wsf + WS_OUTVB);
    float* rws   = wsf + WS_R;
    unsigned short* wkp = (unsigned short*)rws;   // aliases rws head; dead before gemm_fc writes rws
    float* outp     = (float*)d_out;
    float* attn_out = outp + (size_t)B_ * D_;

    prep2<<<256, 256, 0, stream>>>(Wk, wmap, W1, W2, Wv, Wfc, mask, flagp,
                                   wkp, W1t, W2t, Wvb, Wfcb);
    attn_v3<<<B_, 512, 0, stream>>>(seq, seq_e, seq_t, mask, wkp, flagp, ctxb, attn_out);
    gemm_v_mfma<<<dim3(64, 6), 256, 0, stream>>>(ctxb, Wvb, outvb);
    gemm_fc_mfma<<<dim3(64, 6), 256, 0, stream>>>(outvb, Wfcb, bfc, src, src_s, src_t, rws);
    ln_mlp<<<512, 256, 0, stream>>>(rws, src, ln_g, ln_b, W1t, b1, W2t, b2, outp);
}